// Round 14
// baseline (218.924 us; speedup 1.0000x reference)
//
#include <hip/hip_runtime.h>
#include <stdint.h>

// SelfAttention: x[4,2048,1024] fp32, mask[4,2048,2048] int32 (all ones),
// Wq/Wk/Wv/Wo [1024,1024], biases [1024] (zeros).
// out = softmax((xWq+bq)(xWk+bk)^T / 8, mask) (xWv+bv) Wo + bo   (per head, hd=64)

#define SS 2048
#define NH 16

typedef __bf16 bf16x8 __attribute__((ext_vector_type(8)));
typedef float f32x4 __attribute__((ext_vector_type(4)));

__device__ __forceinline__ unsigned short f2bf(float f) {
  union { float f; unsigned int u; } v; v.f = f;
  unsigned int u = v.u;
  return (unsigned short)((u + 0x7fffu + ((u >> 16) & 1u)) >> 16);
}

__device__ __forceinline__ unsigned int cvtpk(float a, float b) {  // lo=bf16(a), hi=bf16(b)
  unsigned int r;
  asm("v_cvt_pk_bf16_f32 %0, %1, %2" : "=v"(r) : "v"(a), "v"(b));
  return r;
}

__device__ __forceinline__ float ex2(float x) {  // v_exp_f32: 2^x
  float r; asm("v_exp_f32 %0, %1" : "=v"(r) : "v"(x)); return r;
}

// A' = {A.lo32, B.lo32}, B' = {A.hi32, B.hi32}
__device__ __forceinline__ void swap32(unsigned int& a, unsigned int& b) {
  asm volatile("v_permlane32_swap_b32 %0, %1" : "+v"(a), "+v"(b));
}
// A' = {A.r0, B.r0, A.r2, B.r2}, B' = {A.r1, B.r1, A.r3, B.r3}  (16-lane rows)
__device__ __forceinline__ void swap16(unsigned int& a, unsigned int& b) {
  asm volatile("v_permlane16_swap_b32 %0, %1" : "+v"(a), "+v"(b));
}

__device__ __forceinline__ void gload_lds16(const void* g, void* l) {
  __builtin_amdgcn_global_load_lds(
      (__attribute__((address_space(1))) void*)(void*)g,
      (__attribute__((address_space(3))) void*)l,
      16, 0, 0);
}

// ---------------- fused preprocessing: conv_x | transW | maskflags -----------
__global__ __launch_bounds__(256) void k_prep(const float* __restrict__ x,
                                              const float* __restrict__ W0,
                                              const float* __restrict__ W1,
                                              const float* __restrict__ W2,
                                              const float* __restrict__ W3,
                                              const int* __restrict__ mask,
                                              unsigned short* __restrict__ xb,
                                              unsigned short* __restrict__ Wt,
                                              int* __restrict__ flg) {
  __shared__ float t[64][65];
  __shared__ int s4[4];
  const int bid = blockIdx.x;
  const int tid = threadIdx.x;

  if (bid < 8192) {  // conv_x
    long i = ((long)bid * 256 + tid) * 4;
    float4 v = *(const float4*)(x + i);
    uint2 o;
    o.x = cvtpk(v.x, v.y);
    o.y = cvtpk(v.z, v.w);
    *(uint2*)(xb + i) = o;
  } else if (bid < 9216) {  // transW
    int inner = bid - 8192;
    int bx = inner & 15, by = (inner >> 4) & 15, bz = inner >> 8;
    const float* W = bz == 0 ? W0 : bz == 1 ? W1 : bz == 2 ? W2 : W3;
    unsigned short* dst = Wt + (size_t)bz * 1024 * 1024;
    int r0 = by * 64, c0 = bx * 64;
    int tr = tid >> 6, tc = tid & 63;
#pragma unroll
    for (int i = 0; i < 16; i++) {
      int r = tr + i * 4;
      t[r][tc] = W[(size_t)(r0 + r) * 1024 + c0 + tc];
    }
    __syncthreads();
#pragma unroll
    for (int i = 0; i < 16; i++) {
      int r = tr + i * 4;
      dst[(size_t)(c0 + r) * 1024 + r0 + tc] = f2bf(t[tc][r]);
    }
  } else {  // maskflags
    int inner = bid - 9216;
    int kt = inner & 31, qb = (inner >> 5) & 15, b = inner >> 9;
    const int* M = mask + ((size_t)b * SS + qb * 128) * SS + kt * 64;
    int ok = 1;
#pragma unroll
    for (int i = 0; i < 8; i++) {
      int r = (tid >> 4) + i * 16;
      int4 v = *(const int4*)(M + (size_t)r * SS + (tid & 15) * 4);
      ok &= (v.x != 0) & (v.y != 0) & (v.z != 0) & (v.w != 0);
    }
    ok = __all(ok) ? 1 : 0;
    if ((tid & 63) == 0) s4[tid >> 6] = ok;
    __syncthreads();
    if (tid == 0) flg[((size_t)b * 16 + qb) * 32 + kt] = s4[0] & s4[1] & s4[2] & s4[3];
  }
}

// ---------------- fused QKV GEMM: 1536 blocks = 3 mats x 512 ----------------
__global__ __launch_bounds__(256) void k_gemmQKV(const unsigned short* __restrict__ A,
                                                 const unsigned short* __restrict__ Wt,
                                                 const float* __restrict__ bq,
                                                 const float* __restrict__ bk,
                                                 const float* __restrict__ bv,
                                                 unsigned short* __restrict__ Qb,
                                                 unsigned short* __restrict__ Kb,
                                                 unsigned short* __restrict__ Vtp) {
  constexpr int K = 1024, N = 1024;
  __shared__ unsigned short lA[128 * 64];
  __shared__ unsigned short lB[128 * 64];
  const int tid = threadIdx.x;
  const int lane = tid & 63, wave = tid >> 6;
  const int wr = wave >> 1, wc = wave & 1;
  const int g = lane >> 4, c = lane & 15;

  const int mat = blockIdx.x >> 9;
  const int inner = blockIdx.x & 511;
  const int xcd = inner & 7, idx = inner >> 3;
  const int by = xcd * 8 + (idx >> 3), bx = idx & 7;
  const long brow = (long)by * 128, bcol = (long)bx * 128;

  const unsigned short* Bt = Wt + ((size_t)mat << 20);
  const float* bias = mat == 0 ? bq : (mat == 1 ? bk : bv);

  f32x4 acc[4][4] = {};

  int sr[4], sch[4];
#pragma unroll
  for (int j = 0; j < 4; j++) {
    int p = j * 4096 + tid * 16;
    int r = p >> 7;
    int sl = (p >> 4) & 7;
    sr[j] = r;
    sch[j] = (sl ^ (r & 7)) * 8;
  }
  char* lbaseA = (char*)lA + wave * 1024;
  char* lbaseB = (char*)lB + wave * 1024;

  for (int k0 = 0; k0 < K; k0 += 64) {
#pragma unroll
    for (int j = 0; j < 4; j++) {
      gload_lds16(A + (brow + sr[j]) * K + k0 + sch[j], lbaseA + j * 4096);
      gload_lds16(Bt + (bcol + sr[j]) * K + k0 + sch[j], lbaseB + j * 4096);
    }
    __syncthreads();
#pragma unroll
    for (int ks = 0; ks < 2; ks++) {
      bf16x8 af[4], bfr[4];
#pragma unroll
      for (int m = 0; m < 4; m++) {
        int ra = wr * 64 + m * 16 + c;
        af[m] = *(const bf16x8*)((const char*)lA + ra * 128 + ((ks * 64 + g * 16) ^ ((ra & 7) << 4)));
        int rb = wc * 64 + m * 16 + c;
        bfr[m] = *(const bf16x8*)((const char*)lB + rb * 128 + ((ks * 64 + g * 16) ^ ((rb & 7) << 4)));
      }
      __builtin_amdgcn_s_setprio(1);
#pragma unroll
      for (int m = 0; m < 4; m++)
#pragma unroll
        for (int n = 0; n < 4; n++)
          acc[m][n] = __builtin_amdgcn_mfma_f32_16x16x32_bf16(af[m], bfr[n], acc[m][n], 0, 0, 0);
      __builtin_amdgcn_s_setprio(0);
    }
    __syncthreads();
  }

  const float scale = (mat == 0) ? 0.180336880111120f /*0.125*log2(e)*/ : 1.0f;
#pragma unroll
  for (int m = 0; m < 4; m++) {
#pragma unroll
    for (int n = 0; n < 4; n++) {
      long row0 = brow + wr * 64 + m * 16 + g * 4;
      long col = bcol + wc * 64 + n * 16 + c;
      float bv_ = bias[col];
      if (mat == 2) {  // V: transposed per-head write -> Vt[b][h][d][s]
        long b_ = row0 >> 11, s = row0 & 2047;
        size_t base = ((size_t)(b_ * NH + (col >> 6)) * 64 + (col & 63)) * SS + s;
        ushort4 pk;
        pk.x = f2bf(acc[m][n][0] + bv_);
        pk.y = f2bf(acc[m][n][1] + bv_);
        pk.z = f2bf(acc[m][n][2] + bv_);
        pk.w = f2bf(acc[m][n][3] + bv_);
        *(ushort4*)(Vtp + base) = pk;
      } else {
        unsigned short* C = mat ? Kb : Qb;
#pragma unroll
        for (int r = 0; r < 4; r++)
          C[(row0 + r) * N + col] = f2bf((acc[m][n][r] + bv_) * scale);
      }
    }
  }
}

// ---------------- O-projection GEMM (fp32 out) ----------------
__global__ __launch_bounds__(256) void k_gemmO(const unsigned short* __restrict__ A,
                                               const unsigned short* __restrict__ Bt,
                                               const float* __restrict__ bias,
                                               float* __restrict__ Cout) {
  constexpr int K = 1024, N = 1024;
  __shared__ unsigned short lA[128 * 64];
  __shared__ unsigned short lB[128 * 64];
  const int tid = threadIdx.x;
  const int lane = tid & 63, wave = tid >> 6;
  const int wr = wave >> 1, wc = wave & 1;
  const int g = lane >> 4, c = lane & 15;

  const int bid = blockIdx.x;
  const int xcd = bid & 7, idx = bid >> 3;
  const int by = xcd * 8 + (idx >> 3), bx = idx & 7;
  const long brow = (long)by * 128, bcol = (long)bx * 128;

  f32x4 acc[4][4] = {};

  int sr[4], sch[4];
#pragma unroll
  for (int j = 0; j < 4; j++) {
    int p = j * 4096 + tid * 16;
    int r = p >> 7;
    int sl = (p >> 4) & 7;
    sr[j] = r;
    sch[j] = (sl ^ (r & 7)) * 8;
  }
  char* lbaseA = (char*)lA + wave * 1024;
  char* lbaseB = (char*)lB + wave * 1024;

  for (int k0 = 0; k0 < K; k0 += 64) {
#pragma unroll
    for (int j = 0; j < 4; j++) {
      gload_lds16(A + (brow + sr[j]) * K + k0 + sch[j], lbaseA + j * 4096);
      gload_lds16(Bt + (bcol + sr[j]) * K + k0 + sch[j], lbaseB + j * 4096);
    }
    __syncthreads();
#pragma unroll
    for (int ks = 0; ks < 2; ks++) {
      bf16x8 af[4], bfr[4];
#pragma unroll
      for (int m = 0; m < 4; m++) {
        int ra = wr * 64 + m * 16 + c;
        af[m] = *(const bf16x8*)((const char*)lA + ra * 128 + ((ks * 64 + g * 16) ^ ((ra & 7) << 4)));
        int rb = wc * 64 + m * 16 + c;
        bfr[m] = *(const bf16x8*)((const char*)lB + rb * 128 + ((ks * 64 + g * 16) ^ ((rb & 7) << 4)));
      }
      __builtin_amdgcn_s_setprio(1);
#pragma unroll
      for (int m = 0; m < 4; m++)
#pragma unroll
        for (int n = 0; n < 4; n++)
          acc[m][n] = __builtin_amdgcn_mfma_f32_16x16x32_bf16(af[m], bfr[n], acc[m][n], 0, 0, 0);
      __builtin_amdgcn_s_setprio(0);
    }
    __syncthreads();
  }

#pragma unroll
  for (int m = 0; m < 4; m++) {
#pragma unroll
    for (int n = 0; n < 4; n++) {
      long row0 = brow + wr * 64 + m * 16 + g * 4;
      long col = bcol + wc * 64 + n * 16 + c;
      float bv = bias[col];
#pragma unroll
      for (int r = 0; r < 4; r++)
        Cout[(row0 + r) * N + col] = acc[m][n][r] + bv;
    }
  }
}

// ---------------- flash attention (high-occupancy variant) ----------------
// R7 pipeline reparameterized: QBLK=64/block (4 waves x 16 q), KVBLK=32.
// LDS = 3 K slots + 2 V slots x 4KB = 20KB -> 8 blocks/CU = 32 waves/CU (max).
// Counted vmcnt: steady wait vmcnt(1) (K dist-2, V dist-1, 1 gload each).
// Same swapped QK^T + guard softmax + permlane P-redistribution as R7.
// Score tile S^T: [key = ct*16+g*4+r][q = c], ct in {0,1}.
__global__ __launch_bounds__(256, 4) void k_flash(const unsigned short* __restrict__ Q,
                                                  const unsigned short* __restrict__ Kb,
                                                  const unsigned short* __restrict__ Vt,
                                                  const int* __restrict__ mask,
                                                  const int* __restrict__ flg,
                                                  unsigned short* __restrict__ O) {
  __shared__ unsigned short lK[3][2048];   // 3 K slots (12 KB): [32 key][64 d] swz rows
  __shared__ unsigned short lV[2][2048];   // 2 V slots (8 KB):  [64 d][32 key] swz rows
  const int tid = threadIdx.x, lane = tid & 63, w = tid >> 6;
  const int g = lane >> 4, c = lane & 15;

  const int bid = blockIdx.x;             // 2048 = 8 xcd x 8 Ghi x 32 qb
  const int xcd = bid & 7, jj = bid >> 3;
  const int qb = jj & 31, Ghi = jj >> 5;
  const int G = xcd * 8 + Ghi;
  const int h = G & 15, b = G >> 4;

  const int q0 = qb * 64 + w * 16;
  const long mrow0 = (long)b * SS + q0;

  const unsigned short* Kbase = Kb + (size_t)b * SS * 1024 + h * 64;
  const unsigned short* Vbase = Vt + (size_t)((b * NH + h) * 64) * SS;
  const int* Mbase = mask + ((size_t)b * SS + q0) * SS;
  const int* Fbase = flg + ((size_t)b * 16 + (q0 >> 7)) * 32;

  // uniform "all tiles unmasked" flag (these loads age older than staging)
  int allok = 1;
#pragma unroll
  for (int i = 0; i < 32; i++) allok &= Fbase[i];
  allok = __builtin_amdgcn_readfirstlane(allok);

  // Q fragments: 16 q rows per wave
  bf16x8 qf[2];
#pragma unroll
  for (int ks = 0; ks < 2; ks++)
    qf[ks] = *(const bf16x8*)(Q + (mrow0 + c) * 1024 + h * 64 + ks * 32 + g * 8);

  // K staging geometry: tile [32 rows][128 B], swizzle slot8 ^= row&7
  const int pB = tid * 16;
  const int rK = pB >> 7;                            // 0..31
  const int coK = ((((pB >> 4) & 7) ^ (rK & 7))) * 8;
  const unsigned short* gK = Kbase + (size_t)rK * 1024 + coK;
  // V staging geometry: tile [64 rows][64 B], swizzle slot4 ^= (row&3)^((row>>2)&3)
  const int rV = pB >> 6;                            // 0..63
  const int swV = (rV & 3) ^ ((rV >> 2) & 3);
  const int coV = (((pB >> 4) & 3) ^ swV) * 8;
  const unsigned short* gV = Vbase + (size_t)rV * SS + coV;

  char* sk0 = (char*)&lK[0][0];
  char* sk1 = (char*)&lK[1][0];
  char* sk2 = (char*)&lK[2][0];
  char* sv0 = (char*)&lV[0][0];
  char* sv1 = (char*)&lV[1][0];

#define STAGE_K(kt_, dst_) gload_lds16(gK + (size_t)(kt_) * (32 * 1024), (dst_) + pB)
#define STAGE_V(kt_, dst_) gload_lds16(gV + (size_t)(kt_) * 32, (dst_) + pB)

  // prologue ages: K0, V0, K1 -> steady wait vmcnt(1) leaves K(t+1)
  STAGE_K(0, sk0);
  STAGE_V(0, sv0);
  STAGE_K(1, sk1);

  float mst = 8.0f, lst = 0.0f;
  f32x4 o[4] = {};  // O^T frag: [d = ct*16+g*4+r][q = c]

  constexpr int NT = SS / 32;
  for (int kt = 0; kt < NT; kt++) {
    if (kt < NT - 1) asm volatile("s_waitcnt vmcnt(1)" ::: "memory");
    else             asm volatile("s_waitcnt vmcnt(0)" ::: "memory");
    __builtin_amdgcn_s_barrier();
    __builtin_amdgcn_sched_barrier(0);
    if (kt + 1 < NT) STAGE_V(kt + 1, sv1);
    if (kt + 2 < NT) STAGE_K(kt + 2, sk2);

    // K fragments (conflict-free)
    bf16x8 kf[2][2];
#pragma unroll
    for (int ct = 0; ct < 2; ct++)
#pragma unroll
      for (int ks = 0; ks < 2; ks++)
        kf[ct][ks] = *(const bf16x8*)(sk0 + (ct * 16 + c) * 128 +
                                      ((ks * 64 + g * 16) ^ ((c & 7) << 4)));

    // QK^T with C-in = -mst
    f32x4 sc[2];
#pragma unroll
    for (int ct = 0; ct < 2; ct++)
#pragma unroll
      for (int r = 0; r < 4; r++) sc[ct][r] = -mst;
    __builtin_amdgcn_s_setprio(1);
#pragma unroll
    for (int ks = 0; ks < 2; ks++)
#pragma unroll
      for (int ct = 0; ct < 2; ct++)
        sc[ct] = __builtin_amdgcn_mfma_f32_16x16x32_bf16(kf[ct][ks], qf[ks], sc[ct], 0, 0, 0);
    __builtin_amdgcn_s_setprio(0);

    if (!allok) {  // general-mask slow path (never taken for all-ones mask)
      const int key0 = kt * 32;
#pragma unroll
      for (int ct = 0; ct < 2; ct++)
#pragma unroll
        for (int r = 0; r < 4; r++) {
          int mv = Mbase[(size_t)c * SS + key0 + ct * 16 + g * 4 + r];
          if (mv == 0) sc[ct][r] = -1e10f;
        }
    }

    // per-lane guard max (trigger iff true max > mst + 8)
    f32x4 m4;
#pragma unroll
    for (int r = 0; r < 4; r++) m4[r] = fmaxf(sc[0][r], sc[1][r]);
    float pm = fmaxf(fmaxf(m4[0], m4[1]), fmaxf(m4[2], m4[3]));
    if (__any(pm > 8.0f)) {
      float tmv = pm;
      tmv = fmaxf(tmv, __shfl_xor(tmv, 16, 64));
      tmv = fmaxf(tmv, __shfl_xor(tmv, 32, 64));
      float dpos = fmaxf(tmv, 0.0f);
      float sf = ex2(-dpos);
      mst += dpos;
      lst *= sf;
#pragma unroll
      for (int ct = 0; ct < 4; ct++)
#pragma unroll
        for (int r = 0; r < 4; r++) o[ct][r] *= sf;
#pragma unroll
      for (int ct = 0; ct < 2; ct++)
#pragma unroll
        for (int r = 0; r < 4; r++) sc[ct][r] -= dpos;
    }

    // P = 2^sc; per-lane partial row-sum; pack + permlane into PV B-frag
    union PU { unsigned int wd[4]; bf16x8 v; };
    PU pf;
    {
      f32x4 ts4 = {0.0f, 0.0f, 0.0f, 0.0f};
      unsigned int Wd[2][2];
#pragma unroll
      for (int ct = 0; ct < 2; ct++) {
        f32x4 p;
#pragma unroll
        for (int r = 0; r < 4; r++) {
          p[r] = ex2(sc[ct][r]);
          ts4[r] += p[r];
        }
        Wd[ct][0] = cvtpk(p[0], p[1]);
        Wd[ct][1] = cvtpk(p[2], p[3]);
      }
#pragma unroll
      for (int hh = 0; hh < 2; hh++) {
        unsigned int a = Wd[0][hh], bb = Wd[1][hh];
        swap32(a, bb);
        swap16(a, bb);
        pf.wd[hh] = a;
        pf.wd[2 + hh] = bb;
      }
      lst += (ts4[0] + ts4[1]) + (ts4[2] + ts4[3]);
    }

    // V fragments (2-way conflicts = free) + PV
    bf16x8 vf[4];
#pragma unroll
    for (int ct = 0; ct < 4; ct++) {
      int row = ct * 16 + c;
      int sw = ((row & 3) ^ ((row >> 2) & 3)) << 4;
      vf[ct] = *(const bf16x8*)(sv0 + row * 64 + ((g * 16) ^ sw));
    }
    __builtin_amdgcn_s_setprio(1);
#pragma unroll
    for (int ct = 0; ct < 4; ct++)
      o[ct] = __builtin_amdgcn_mfma_f32_16x16x32_bf16(vf[ct], pf.v, o[ct], 0, 0, 0);
    __builtin_amdgcn_s_setprio(0);

    // rotate slots
    char* tk = sk0; sk0 = sk1; sk1 = sk2; sk2 = tk;
    char* tv = sv0; sv0 = sv1; sv1 = tv;
  }

  // epilogue: reduce deferred row-sums (over g-groups), write O
  float t = lst;
  t += __shfl_xor(t, 16, 64);
  t += __shfl_xor(t, 32, 64);
  float inv = 1.0f / t;
#pragma unroll
  for (int ct = 0; ct < 4; ct++) {
    uint2 pk;
    pk.x = cvtpk(o[ct][0] * inv, o[ct][1] * inv);
    pk.y = cvtpk(o[ct][2] * inv, o[ct][3] * inv);
    *(uint2*)(O + (mrow0 + c) * 1024 + h * 64 + ct * 16 + g * 4) = pk;
  }
#undef STAGE_K
#undef STAGE_V
}

extern "C" void kernel_launch(void* const* d_in, const int* in_sizes, int n_in,
                              void* d_out, int out_size, void* d_ws, size_t ws_size,
                              hipStream_t stream) {
  const float* x  = (const float*)d_in[0];
  const int* mask = (const int*)d_in[1];
  const float* Wq = (const float*)d_in[2];
  const float* bq = (const float*)d_in[3];
  const float* Wk = (const float*)d_in[4];
  const float* bk = (const float*)d_in[5];
  const float* Wv = (const float*)d_in[6];
  const float* bv = (const float*)d_in[7];
  const float* Wo = (const float*)d_in[8];
  const float* bo = (const float*)d_in[9];

  char* ws = (char*)d_ws;
  unsigned short* xb = (unsigned short*)ws;                        // 16 MiB (reused as O)
  unsigned short* Wt = (unsigned short*)(ws + (16ull << 20));      // 8 MiB (4 matrices)
  unsigned short* Qb = (unsigned short*)(ws + (24ull << 20));      // 16 MiB
  unsigned short* Kb = (unsigned short*)(ws + (40ull << 20));      // 16 MiB
  unsigned short* Vt = (unsigned short*)(ws + (56ull << 20));      // 16 MiB -> 72 MiB total
  int* flg = (int*)d_out;  // 8 KiB scratch; fully overwritten by final GEMM

  // fused preprocessing (conv_x | transW | maskflags)
  k_prep<<<11264, 256, 0, stream>>>(x, Wq, Wk, Wv, Wo, mask, xb, Wt, flg);
  // fused Q/K/V projections; Q scaled by 0.125*log2(e) (log2-domain softmax)
  k_gemmQKV<<<1536, 256, 0, stream>>>(xb, Wt, bq, bk, bv, Qb, Kb, Vt);
  k_flash<<<2048, 256, 0, stream>>>(Qb, Kb, Vt, mask, flg, xb);
  k_gemmO<<<512, 256, 0, stream>>>(xb, Wt + (3u << 20), bo, (float*)d_out);
}

// Round 15
// 210.983 us; speedup vs baseline: 1.0376x; 1.0376x over previous
//
#include <hip/hip_runtime.h>
#include <stdint.h>

// SelfAttention: x[4,2048,1024] fp32, mask[4,2048,2048] int32 (all ones),
// Wq/Wk/Wv/Wo [1024,1024], biases [1024] (zeros).
// out = softmax((xWq+bq)(xWk+bk)^T / 8, mask) (xWv+bv) Wo + bo   (per head, hd=64)

#define SS 2048
#define NH 16

typedef __bf16 bf16x8 __attribute__((ext_vector_type(8)));
typedef float f32x4 __attribute__((ext_vector_type(4)));

__device__ __forceinline__ unsigned short f2bf(float f) {
  union { float f; unsigned int u; } v; v.f = f;
  unsigned int u = v.u;
  return (unsigned short)((u + 0x7fffu + ((u >> 16) & 1u)) >> 16);
}

__device__ __forceinline__ unsigned int cvtpk(float a, float b) {  // lo=bf16(a), hi=bf16(b)
  unsigned int r;
  asm("v_cvt_pk_bf16_f32 %0, %1, %2" : "=v"(r) : "v"(a), "v"(b));
  return r;
}

__device__ __forceinline__ float ex2(float x) {  // v_exp_f32: 2^x
  float r; asm("v_exp_f32 %0, %1" : "=v"(r) : "v"(x)); return r;
}

// A' = {A.lo32, B.lo32}, B' = {A.hi32, B.hi32}
__device__ __forceinline__ void swap32(unsigned int& a, unsigned int& b) {
  asm volatile("v_permlane32_swap_b32 %0, %1" : "+v"(a), "+v"(b));
}
// A' = {A.r0, B.r0, A.r2, B.r2}, B' = {A.r1, B.r1, A.r3, B.r3}  (16-lane rows)
__device__ __forceinline__ void swap16(unsigned int& a, unsigned int& b) {
  asm volatile("v_permlane16_swap_b32 %0, %1" : "+v"(a), "+v"(b));
}

__device__ __forceinline__ void gload_lds16(const void* g, void* l) {
  __builtin_amdgcn_global_load_lds(
      (__attribute__((address_space(1))) void*)(void*)g,
      (__attribute__((address_space(3))) void*)l,
      16, 0, 0);
}

// ---------------- fused preprocessing: conv_x | transW | maskflags -----------
__global__ __launch_bounds__(256) void k_prep(const float* __restrict__ x,
                                              const float* __restrict__ W0,
                                              const float* __restrict__ W1,
                                              const float* __restrict__ W2,
                                              const float* __restrict__ W3,
                                              const int* __restrict__ mask,
                                              unsigned short* __restrict__ xb,
                                              unsigned short* __restrict__ Wt,
                                              int* __restrict__ flg) {
  __shared__ float t[64][65];
  __shared__ int s4[4];
  const int bid = blockIdx.x;
  const int tid = threadIdx.x;

  if (bid < 8192) {  // conv_x
    long i = ((long)bid * 256 + tid) * 4;
    float4 v = *(const float4*)(x + i);
    uint2 o;
    o.x = cvtpk(v.x, v.y);
    o.y = cvtpk(v.z, v.w);
    *(uint2*)(xb + i) = o;
  } else if (bid < 9216) {  // transW
    int inner = bid - 8192;
    int bx = inner & 15, by = (inner >> 4) & 15, bz = inner >> 8;
    const float* W = bz == 0 ? W0 : bz == 1 ? W1 : bz == 2 ? W2 : W3;
    unsigned short* dst = Wt + (size_t)bz * 1024 * 1024;
    int r0 = by * 64, c0 = bx * 64;
    int tr = tid >> 6, tc = tid & 63;
#pragma unroll
    for (int i = 0; i < 16; i++) {
      int r = tr + i * 4;
      t[r][tc] = W[(size_t)(r0 + r) * 1024 + c0 + tc];
    }
    __syncthreads();
#pragma unroll
    for (int i = 0; i < 16; i++) {
      int r = tr + i * 4;
      dst[(size_t)(c0 + r) * 1024 + r0 + tc] = f2bf(t[tc][r]);
    }
  } else {  // maskflags
    int inner = bid - 9216;
    int kt = inner & 31, qb = (inner >> 5) & 15, b = inner >> 9;
    const int* M = mask + ((size_t)b * SS + qb * 128) * SS + kt * 64;
    int ok = 1;
#pragma unroll
    for (int i = 0; i < 8; i++) {
      int r = (tid >> 4) + i * 16;
      int4 v = *(const int4*)(M + (size_t)r * SS + (tid & 15) * 4);
      ok &= (v.x != 0) & (v.y != 0) & (v.z != 0) & (v.w != 0);
    }
    ok = __all(ok) ? 1 : 0;
    if ((tid & 63) == 0) s4[tid >> 6] = ok;
    __syncthreads();
    if (tid == 0) flg[((size_t)b * 16 + qb) * 32 + kt] = s4[0] & s4[1] & s4[2] & s4[3];
  }
}

// ---------------- fused QKV GEMM: 1536 blocks = 3 mats x 512 ----------------
__global__ __launch_bounds__(256) void k_gemmQKV(const unsigned short* __restrict__ A,
                                                 const unsigned short* __restrict__ Wt,
                                                 const float* __restrict__ bq,
                                                 const float* __restrict__ bk,
                                                 const float* __restrict__ bv,
                                                 unsigned short* __restrict__ Qb,
                                                 unsigned short* __restrict__ Kb,
                                                 unsigned short* __restrict__ Vtp) {
  constexpr int K = 1024, N = 1024;
  __shared__ unsigned short lA[128 * 64];
  __shared__ unsigned short lB[128 * 64];
  const int tid = threadIdx.x;
  const int lane = tid & 63, wave = tid >> 6;
  const int wr = wave >> 1, wc = wave & 1;
  const int g = lane >> 4, c = lane & 15;

  const int mat = blockIdx.x >> 9;
  const int inner = blockIdx.x & 511;
  const int xcd = inner & 7, idx = inner >> 3;
  const int by = xcd * 8 + (idx >> 3), bx = idx & 7;
  const long brow = (long)by * 128, bcol = (long)bx * 128;

  const unsigned short* Bt = Wt + ((size_t)mat << 20);
  const float* bias = mat == 0 ? bq : (mat == 1 ? bk : bv);

  f32x4 acc[4][4] = {};

  int sr[4], sch[4];
#pragma unroll
  for (int j = 0; j < 4; j++) {
    int p = j * 4096 + tid * 16;
    int r = p >> 7;
    int sl = (p >> 4) & 7;
    sr[j] = r;
    sch[j] = (sl ^ (r & 7)) * 8;
  }
  char* lbaseA = (char*)lA + wave * 1024;
  char* lbaseB = (char*)lB + wave * 1024;

  for (int k0 = 0; k0 < K; k0 += 64) {
#pragma unroll
    for (int j = 0; j < 4; j++) {
      gload_lds16(A + (brow + sr[j]) * K + k0 + sch[j], lbaseA + j * 4096);
      gload_lds16(Bt + (bcol + sr[j]) * K + k0 + sch[j], lbaseB + j * 4096);
    }
    __syncthreads();
#pragma unroll
    for (int ks = 0; ks < 2; ks++) {
      bf16x8 af[4], bfr[4];
#pragma unroll
      for (int m = 0; m < 4; m++) {
        int ra = wr * 64 + m * 16 + c;
        af[m] = *(const bf16x8*)((const char*)lA + ra * 128 + ((ks * 64 + g * 16) ^ ((ra & 7) << 4)));
        int rb = wc * 64 + m * 16 + c;
        bfr[m] = *(const bf16x8*)((const char*)lB + rb * 128 + ((ks * 64 + g * 16) ^ ((rb & 7) << 4)));
      }
      __builtin_amdgcn_s_setprio(1);
#pragma unroll
      for (int m = 0; m < 4; m++)
#pragma unroll
        for (int n = 0; n < 4; n++)
          acc[m][n] = __builtin_amdgcn_mfma_f32_16x16x32_bf16(af[m], bfr[n], acc[m][n], 0, 0, 0);
      __builtin_amdgcn_s_setprio(0);
    }
    __syncthreads();
  }

  const float scale = (mat == 0) ? 0.180336880111120f /*0.125*log2(e)*/ : 1.0f;
#pragma unroll
  for (int m = 0; m < 4; m++) {
#pragma unroll
    for (int n = 0; n < 4; n++) {
      long row0 = brow + wr * 64 + m * 16 + g * 4;
      long col = bcol + wc * 64 + n * 16 + c;
      float bv_ = bias[col];
      if (mat == 2) {  // V: transposed per-head write -> Vt[b][h][d][s]
        long b_ = row0 >> 11, s = row0 & 2047;
        size_t base = ((size_t)(b_ * NH + (col >> 6)) * 64 + (col & 63)) * SS + s;
        ushort4 pk;
        pk.x = f2bf(acc[m][n][0] + bv_);
        pk.y = f2bf(acc[m][n][1] + bv_);
        pk.z = f2bf(acc[m][n][2] + bv_);
        pk.w = f2bf(acc[m][n][3] + bv_);
        *(ushort4*)(Vtp + base) = pk;
      } else {
        unsigned short* C = mat ? Kb : Qb;
#pragma unroll
        for (int r = 0; r < 4; r++)
          C[(row0 + r) * N + col] = f2bf((acc[m][n][r] + bv_) * scale);
      }
    }
  }
}

// ---------------- O-projection GEMM (fp32 out) ----------------
__global__ __launch_bounds__(256) void k_gemmO(const unsigned short* __restrict__ A,
                                               const unsigned short* __restrict__ Bt,
                                               const float* __restrict__ bias,
                                               float* __restrict__ Cout) {
  constexpr int K = 1024, N = 1024;
  __shared__ unsigned short lA[128 * 64];
  __shared__ unsigned short lB[128 * 64];
  const int tid = threadIdx.x;
  const int lane = tid & 63, wave = tid >> 6;
  const int wr = wave >> 1, wc = wave & 1;
  const int g = lane >> 4, c = lane & 15;

  const int bid = blockIdx.x;
  const int xcd = bid & 7, idx = bid >> 3;
  const int by = xcd * 8 + (idx >> 3), bx = idx & 7;
  const long brow = (long)by * 128, bcol = (long)bx * 128;

  f32x4 acc[4][4] = {};

  int sr[4], sch[4];
#pragma unroll
  for (int j = 0; j < 4; j++) {
    int p = j * 4096 + tid * 16;
    int r = p >> 7;
    int sl = (p >> 4) & 7;
    sr[j] = r;
    sch[j] = (sl ^ (r & 7)) * 8;
  }
  char* lbaseA = (char*)lA + wave * 1024;
  char* lbaseB = (char*)lB + wave * 1024;

  for (int k0 = 0; k0 < K; k0 += 64) {
#pragma unroll
    for (int j = 0; j < 4; j++) {
      gload_lds16(A + (brow + sr[j]) * K + k0 + sch[j], lbaseA + j * 4096);
      gload_lds16(Bt + (bcol + sr[j]) * K + k0 + sch[j], lbaseB + j * 4096);
    }
    __syncthreads();
#pragma unroll
    for (int ks = 0; ks < 2; ks++) {
      bf16x8 af[4], bfr[4];
#pragma unroll
      for (int m = 0; m < 4; m++) {
        int ra = wr * 64 + m * 16 + c;
        af[m] = *(const bf16x8*)((const char*)lA + ra * 128 + ((ks * 64 + g * 16) ^ ((ra & 7) << 4)));
        int rb = wc * 64 + m * 16 + c;
        bfr[m] = *(const bf16x8*)((const char*)lB + rb * 128 + ((ks * 64 + g * 16) ^ ((rb & 7) << 4)));
      }
      __builtin_amdgcn_s_setprio(1);
#pragma unroll
      for (int m = 0; m < 4; m++)
#pragma unroll
        for (int n = 0; n < 4; n++)
          acc[m][n] = __builtin_amdgcn_mfma_f32_16x16x32_bf16(af[m], bfr[n], acc[m][n], 0, 0, 0);
      __builtin_amdgcn_s_setprio(0);
    }
    __syncthreads();
  }

#pragma unroll
  for (int m = 0; m < 4; m++) {
#pragma unroll
    for (int n = 0; n < 4; n++) {
      long row0 = brow + wr * 64 + m * 16 + g * 4;
      long col = bcol + wc * 64 + n * 16 + c;
      float bv = bias[col];
#pragma unroll
      for (int r = 0; r < 4; r++)
        Cout[(row0 + r) * N + col] = acc[m][n][r] + bv;
    }
  }
}

// ---------------- flash attention (R13 structure + C-in broadcast) ----------
// Swapped QK^T + in-register softmax + counted-vmcnt pipeline (K dist-2 /
// 3 slots, V dist-1 / 2 slots, steady wait vmcnt(2), 1 barrier/tile, never
// drain-0 in-loop). Guard-based softmax (mst init 8.0, log2 domain).
// NEW: -mst folded into QK^T C-in via persistent broadcast regs mstv[rt]
// (updated only in the rare rescale branch) — kills 32 v_mov per tile.
// Score tile S^T = mfma(K,Q): [key = ct*16+g*4+r][q = rt*16+c].
__global__ __launch_bounds__(256, 4) void k_flash(const unsigned short* __restrict__ Q,
                                                  const unsigned short* __restrict__ Kb,
                                                  const unsigned short* __restrict__ Vt,
                                                  const int* __restrict__ mask,
                                                  const int* __restrict__ flg,
                                                  unsigned short* __restrict__ O) {
  __shared__ unsigned short lK[3][4096];   // 3 K slots (24 KB), swizzled rows
  __shared__ unsigned short lV[2][4096];   // 2 V slots (16 KB), swizzled rows
  const int tid = threadIdx.x, lane = tid & 63, w = tid >> 6;
  const int g = lane >> 4, c = lane & 15;

  const int bid = blockIdx.x;
  const int xcd = bid & 7, jj = bid >> 3;
  const int qb = jj & 15, Ghi = jj >> 4;
  const int G = xcd * 8 + Ghi;
  const int h = G & 15, b = G >> 4;

  const int q0 = qb * 128 + w * 32;
  const long mrow0 = (long)b * SS + q0;

  const unsigned short* Kbase = Kb + (size_t)b * SS * 1024 + h * 64;
  const unsigned short* Vbase = Vt + (size_t)((b * NH + h) * 64) * SS;
  const int* Mbase = mask + ((size_t)b * SS + q0) * SS;
  const int* Fbase = flg + ((size_t)b * 16 + qb) * 32;

  // uniform "all tiles unmasked" flag (loads age older than all staging loads)
  int allok = 1;
#pragma unroll
  for (int i = 0; i < 32; i++) allok &= Fbase[i];
  allok = __builtin_amdgcn_readfirstlane(allok);

  // Q fragments (registers for whole kernel)
  bf16x8 qf[2][2];
#pragma unroll
  for (int rt = 0; rt < 2; rt++)
#pragma unroll
    for (int ks = 0; ks < 2; ks++)
      qf[rt][ks] = *(const bf16x8*)(Q + (mrow0 + rt * 16 + c) * 1024 + h * 64 + ks * 32 + g * 8);

  // staging: linear LDS dest; pre-swizzled global source (tile row r holds
  // 16B-slot t = source slot t^(r&7))
  const int pB = tid * 16;
  const int r0 = pB >> 7;
  const int co = (((pB >> 4) & 7) ^ (r0 & 7)) * 8;
  const unsigned short* gK = Kbase + (size_t)r0 * 1024 + co;
  const unsigned short* gV = Vbase + (size_t)r0 * SS + co;
  const int wb = w * 1024;

  char* sk0 = (char*)&lK[0][0];
  char* sk1 = (char*)&lK[1][0];
  char* sk2 = (char*)&lK[2][0];
  char* sv0 = (char*)&lV[0][0];
  char* sv1 = (char*)&lV[1][0];

#define STAGE_K(kt_, dst_) do { \
    const unsigned short* aK_ = gK + (size_t)(kt_) * (64 * 1024); \
    gload_lds16(aK_, (dst_) + wb); \
    gload_lds16(aK_ + 32 * 1024, (dst_) + wb + 4096); } while (0)
#define STAGE_V(kt_, dst_) do { \
    const unsigned short* aV_ = gV + (size_t)(kt_) * 64; \
    gload_lds16(aV_, (dst_) + wb); \
    gload_lds16(aV_ + 32 * (size_t)SS, (dst_) + wb + 4096); } while (0)

  // prologue issue order (ages): K0, V0, K1  -> vmcnt(2) at iter0 leaves K1
  STAGE_K(0, sk0);
  STAGE_V(0, sv0);
  STAGE_K(1, sk1);

  float mst[2] = {8.0f, 8.0f}, lst[2] = {0.0f, 0.0f};
  f32x4 mstv[2];  // persistent broadcast of -mst (QK^T C-in); updated only on rescale
#pragma unroll
  for (int rt = 0; rt < 2; rt++)
#pragma unroll
    for (int r = 0; r < 4; r++) mstv[rt][r] = -8.0f;
  f32x4 o[2][4] = {};  // O^T frag: [d = ct*16+g*4+r][q = rt*16+c]

  for (int kt = 0; kt < SS / 64; kt++) {
    // wait for K(kt) and V(kt); leaves K(kt+1) in flight (2 loads)
    if (kt < SS / 64 - 1) asm volatile("s_waitcnt vmcnt(2)" ::: "memory");
    else                  asm volatile("s_waitcnt vmcnt(0)" ::: "memory");
    __builtin_amdgcn_s_barrier();
    __builtin_amdgcn_sched_barrier(0);
    // issue next tiles: V(kt+1) FIRST (must age older than K(kt+2))
    if (kt + 1 < SS / 64) STAGE_V(kt + 1, sv1);
    if (kt + 2 < SS / 64) STAGE_K(kt + 2, sk2);

    // K fragments (conflict-free via XOR swizzle)
    bf16x8 kf[4][2];
#pragma unroll
    for (int ct = 0; ct < 4; ct++)
#pragma unroll
      for (int ks = 0; ks < 2; ks++)
        kf[ct][ks] = *(const bf16x8*)(sk0 + (ct * 16 + c) * 128 +
                                      ((ks * 64 + g * 16) ^ ((c & 7) << 4)));

    // QK^T: first K-slice uses C-in = mstv (pre-shifted scores), second accumulates
    f32x4 sc[2][4];
    __builtin_amdgcn_s_setprio(1);
#pragma unroll
    for (int rt = 0; rt < 2; rt++)
#pragma unroll
      for (int ct = 0; ct < 4; ct++)
        sc[rt][ct] = __builtin_amdgcn_mfma_f32_16x16x32_bf16(kf[ct][0], qf[rt][0], mstv[rt], 0, 0, 0);
#pragma unroll
    for (int rt = 0; rt < 2; rt++)
#pragma unroll
      for (int ct = 0; ct < 4; ct++)
        sc[rt][ct] = __builtin_amdgcn_mfma_f32_16x16x32_bf16(kf[ct][1], qf[rt][1], sc[rt][ct], 0, 0, 0);
    __builtin_amdgcn_s_setprio(0);

    if (!allok) {  // general-mask slow path (never taken for all-ones mask)
      const int key0 = kt * 64;
#pragma unroll
      for (int rt = 0; rt < 2; rt++)
#pragma unroll
        for (int ct = 0; ct < 4; ct++)
#pragma unroll
          for (int r = 0; r < 4; r++) {
            int mv = Mbase[(size_t)(rt * 16 + c) * SS + key0 + ct * 16 + g * 4 + r];
            if (mv == 0) sc[rt][ct][r] = -1e10f;
          }
    }

    // per-lane guard max (trigger iff true max > mst + 8)
    float pm[2];
#pragma unroll
    for (int rt = 0; rt < 2; rt++) {
      f32x4 m4;
#pragma unroll
      for (int r = 0; r < 4; r++)
        m4[r] = fmaxf(fmaxf(sc[rt][0][r], sc[rt][1][r]), fmaxf(sc[rt][2][r], sc[rt][3][r]));
      pm[rt] = fmaxf(fmaxf(m4[0], m4[1]), fmaxf(m4[2], m4[3]));
    }
    if (__any((pm[0] > 8.0f) | (pm[1] > 8.0f))) {
      // rare full rescale: factors are row-uniform after the cross-lane max
#pragma unroll
      for (int rt = 0; rt < 2; rt++) {
        float tmv = pm[rt];
        tmv = fmaxf(tmv, __shfl_xor(tmv, 16, 64));
        tmv = fmaxf(tmv, __shfl_xor(tmv, 32, 64));
        float dpos = fmaxf(tmv, 0.0f);   // mnew - mold
        float sf = ex2(-dpos);
        mst[rt] += dpos;
        lst[rt] *= sf;
#pragma unroll
        for (int r = 0; r < 4; r++) mstv[rt][r] = -mst[rt];
#pragma unroll
        for (int ct = 0; ct < 4; ct++)
#pragma unroll
          for (int r = 0; r < 4; r++) { o[rt][ct][r] *= sf; sc[rt][ct][r] -= dpos; }
      }
    }

    // P = 2^sc; per-lane partial row-sum (reduced once in epilogue);
    // pack + permlane-redistribute into PV B-fragments (no LDS)
    union PU { unsigned int wd[4]; bf16x8 v; };
    PU pf[2][2];
#pragma unroll
    for (int rt = 0; rt < 2; rt++) {
      f32x4 ts4 = {0.0f, 0.0f, 0.0f, 0.0f};
      unsigned int Wd[4][2];
#pragma unroll
      for (int ct = 0; ct < 4; ct++) {
        f32x4 p;
#pragma unroll
        for (int r = 0; r < 4; r++) {
          p[r] = ex2(sc[rt][ct][r]);
          ts4[r] += p[r];
        }
        Wd[ct][0] = cvtpk(p[0], p[1]);
        Wd[ct][1] = cvtpk(p[2], p[3]);
      }
#pragma unroll
      for (int ks = 0; ks < 2; ks++)
#pragma unroll
        for (int hh = 0; hh < 2; hh++) {
          unsigned int a = Wd[2 * ks][hh], bb = Wd[2 * ks + 1][hh];
          swap32(a, bb);  // a={A_lo,B_lo}, bb={A_hi,B_hi}
          swap16(a, bb);  // interleave 4-row groups
          pf[rt][ks].wd[hh] = a;
          pf[rt][ks].wd[2 + hh] = bb;
        }
      lst[rt] += (ts4[0] + ts4[1]) + (ts4[2] + ts4[3]);
    }

    // V fragments + PV
    bf16x8 vf[4][2];
#pragma unroll
    for (int ct = 0; ct < 4; ct++)
#pragma unroll
      for (int ks = 0; ks < 2; ks++)
        vf[ct][ks] = *(const bf16x8*)(sv0 + (ct * 16 + c) * 128 +
                                      ((ks * 64 + g * 16) ^ ((c & 7) << 4)));
    __builtin_amdgcn_s_setprio(1);
#pragma unroll
    for (int rt = 0; rt < 2; rt++)
#pragma unroll
      for (int ct = 0; ct < 4; ct++)
#pragma unroll
        for (int ks = 0; ks < 2; ks++)
          o[rt][ct] = __builtin_amdgcn_mfma_f32_16x16x32_bf16(vf[ct][ks], pf[rt][ks].v, o[rt][ct], 0, 0, 0);
    __builtin_amdgcn_s_setprio(0);

    // rotate slots
    char* tk = sk0; sk0 = sk1; sk1 = sk2; sk2 = tk;
    char* tv = sv0; sv0 = sv1; sv1 = tv;
  }

  // epilogue: one cross-lane reduce of the deferred row-sums, then write O
#pragma unroll
  for (int rt = 0; rt < 2; rt++) {
    float t = lst[rt];
    t += __shfl_xor(t, 16, 64);
    t += __shfl_xor(t, 32, 64);
    float inv = 1.0f / t;
#pragma unroll
    for (int ct = 0; ct < 4; ct++) {
      uint2 pk;
      pk.x = cvtpk(o[rt][ct][0] * inv, o[rt][ct][1] * inv);
      pk.y = cvtpk(o[rt][ct][2] * inv, o[rt][ct][3] * inv);
      *(uint2*)(O + (mrow0 + rt * 16 + c) * 1024 + h * 64 + ct * 16 + g * 4) = pk;
    }
  }
#undef STAGE_K
#undef STAGE_V
}

extern "C" void kernel_launch(void* const* d_in, const int* in_sizes, int n_in,
                              void* d_out, int out_size, void* d_ws, size_t ws_size,
                              hipStream_t stream) {
  const float* x  = (const float*)d_in[0];
  const int* mask = (const int*)d_in[1];
  const float* Wq = (const float*)d_in[2];
  const float* bq = (const float*)d_in[3];
  const float* Wk = (const float*)d_in[4];
  const float* bk = (const float*)d_in[5];
  const float* Wv = (const float*)d_in[6];
  const float* bv = (const float*)d_in[7];
  const float* Wo = (const float*)d_in[8];
  const float* bo = (const float*)d_in[9];

  char* ws = (char*)d_ws;
  unsigned short* xb = (unsigned short*)ws;                        // 16 MiB (reused as O)
  unsigned short* Wt = (unsigned short*)(ws + (16ull << 20));      // 8 MiB (4 matrices)
  unsigned short* Qb = (unsigned short*)(ws + (24ull << 20));      // 16 MiB
  unsigned short* Kb = (unsigned short*)(ws + (40ull << 20));      // 16 MiB
  unsigned short* Vt = (unsigned short*)(ws + (56ull << 20));      // 16 MiB -> 72 MiB total
  int* flg = (int*)d_out;  // 8 KiB scratch; fully overwritten by final GEMM

  // fused preprocessing (conv_x | transW | maskflags)
  k_prep<<<11264, 256, 0, stream>>>(x, Wq, Wk, Wv, Wo, mask, xb, Wt, flg);
  // fused Q/K/V projections; Q scaled by 0.125*log2(e) (log2-domain softmax)
  k_gemmQKV<<<1536, 256, 0, stream>>>(xb, Wt, bq, bk, bv, Qb, Kb, Vt);
  k_flash<<<1024, 256, 0, stream>>>(Qb, Kb, Vt, mask, flg, xb);
  k_gemmO<<<512, 256, 0, stream>>>(xb, Wt + (3u << 20), bo, (float*)d_out);
}

// Round 17
// 200.040 us; speedup vs baseline: 1.0944x; 1.0547x over previous
//
#include <hip/hip_runtime.h>
#include <stdint.h>

// SelfAttention: x[4,2048,1024] fp32, mask[4,2048,2048] int32 (all ones),
// Wq/Wk/Wv/Wo [1024,1024], biases [1024] (zeros).
// out = softmax((xWq+bq)(xWk+bk)^T / 8, mask) (xWv+bv) Wo + bo   (per head, hd=64)

#define SS 2048
#define NH 16

typedef __bf16 bf16x8 __attribute__((ext_vector_type(8)));
typedef float f32x4 __attribute__((ext_vector_type(4)));

__device__ __forceinline__ unsigned short f2bf(float f) {
  union { float f; unsigned int u; } v; v.f = f;
  unsigned int u = v.u;
  return (unsigned short)((u + 0x7fffu + ((u >> 16) & 1u)) >> 16);
}

__device__ __forceinline__ unsigned int cvtpk(float a, float b) {  // lo=bf16(a), hi=bf16(b)
  unsigned int r;
  asm("v_cvt_pk_bf16_f32 %0, %1, %2" : "=v"(r) : "v"(a), "v"(b));
  return r;
}

__device__ __forceinline__ float ex2(float x) {  // v_exp_f32: 2^x
  float r; asm("v_exp_f32 %0, %1" : "=v"(r) : "v"(x)); return r;
}

// A' = {A.lo32, B.lo32}, B' = {A.hi32, B.hi32}
__device__ __forceinline__ void swap32(unsigned int& a, unsigned int& b) {
  asm volatile("v_permlane32_swap_b32 %0, %1" : "+v"(a), "+v"(b));
}
// A' = {A.r0, B.r0, A.r2, B.r2}, B' = {A.r1, B.r1, A.r3, B.r3}  (16-lane rows)
__device__ __forceinline__ void swap16(unsigned int& a, unsigned int& b) {
  asm volatile("v_permlane16_swap_b32 %0, %1" : "+v"(a), "+v"(b));
}

__device__ __forceinline__ void gload_lds16(const void* g, void* l) {
  __builtin_amdgcn_global_load_lds(
      (__attribute__((address_space(1))) void*)(void*)g,
      (__attribute__((address_space(3))) void*)l,
      16, 0, 0);
}

// ---------------- fused preprocessing: conv_x | transW | maskflags -----------
__global__ __launch_bounds__(256) void k_prep(const float* __restrict__ x,
                                              const float* __restrict__ W0,
                                              const float* __restrict__ W1,
                                              const float* __restrict__ W2,
                                              const float* __restrict__ W3,
                                              const int* __restrict__ mask,
                                              unsigned short* __restrict__ xb,
                                              unsigned short* __restrict__ Wt,
                                              int* __restrict__ flg) {
  __shared__ float t[64][65];
  __shared__ int s4[4];
  const int bid = blockIdx.x;
  const int tid = threadIdx.x;

  if (bid < 8192) {  // conv_x
    long i = ((long)bid * 256 + tid) * 4;
    float4 v = *(const float4*)(x + i);
    uint2 o;
    o.x = cvtpk(v.x, v.y);
    o.y = cvtpk(v.z, v.w);
    *(uint2*)(xb + i) = o;
  } else if (bid < 9216) {  // transW
    int inner = bid - 8192;
    int bx = inner & 15, by = (inner >> 4) & 15, bz = inner >> 8;
    const float* W = bz == 0 ? W0 : bz == 1 ? W1 : bz == 2 ? W2 : W3;
    unsigned short* dst = Wt + (size_t)bz * 1024 * 1024;
    int r0 = by * 64, c0 = bx * 64;
    int tr = tid >> 6, tc = tid & 63;
#pragma unroll
    for (int i = 0; i < 16; i++) {
      int r = tr + i * 4;
      t[r][tc] = W[(size_t)(r0 + r) * 1024 + c0 + tc];
    }
    __syncthreads();
#pragma unroll
    for (int i = 0; i < 16; i++) {
      int r = tr + i * 4;
      dst[(size_t)(c0 + r) * 1024 + r0 + tc] = f2bf(t[tc][r]);
    }
  } else {  // maskflags
    int inner = bid - 9216;
    int kt = inner & 31, qb = (inner >> 5) & 15, b = inner >> 9;
    const int* M = mask + ((size_t)b * SS + qb * 128) * SS + kt * 64;
    int ok = 1;
#pragma unroll
    for (int i = 0; i < 8; i++) {
      int r = (tid >> 4) + i * 16;
      int4 v = *(const int4*)(M + (size_t)r * SS + (tid & 15) * 4);
      ok &= (v.x != 0) & (v.y != 0) & (v.z != 0) & (v.w != 0);
    }
    ok = __all(ok) ? 1 : 0;
    if ((tid & 63) == 0) s4[tid >> 6] = ok;
    __syncthreads();
    if (tid == 0) flg[((size_t)b * 16 + qb) * 32 + kt] = s4[0] & s4[1] & s4[2] & s4[3];
  }
}

// ---------------- fused QKV GEMM: 1536 blocks = 3 mats x 512 ----------------
__global__ __launch_bounds__(256) void k_gemmQKV(const unsigned short* __restrict__ A,
                                                 const unsigned short* __restrict__ Wt,
                                                 const float* __restrict__ bq,
                                                 const float* __restrict__ bk,
                                                 const float* __restrict__ bv,
                                                 unsigned short* __restrict__ Qb,
                                                 unsigned short* __restrict__ Kb,
                                                 unsigned short* __restrict__ Vtp) {
  constexpr int K = 1024, N = 1024;
  __shared__ unsigned short lA[128 * 64];
  __shared__ unsigned short lB[128 * 64];
  const int tid = threadIdx.x;
  const int lane = tid & 63, wave = tid >> 6;
  const int wr = wave >> 1, wc = wave & 1;
  const int g = lane >> 4, c = lane & 15;

  const int mat = blockIdx.x >> 9;
  const int inner = blockIdx.x & 511;
  const int xcd = inner & 7, idx = inner >> 3;
  const int by = xcd * 8 + (idx >> 3), bx = idx & 7;
  const long brow = (long)by * 128, bcol = (long)bx * 128;

  const unsigned short* Bt = Wt + ((size_t)mat << 20);
  const float* bias = mat == 0 ? bq : (mat == 1 ? bk : bv);

  f32x4 acc[4][4] = {};

  int sr[4], sch[4];
#pragma unroll
  for (int j = 0; j < 4; j++) {
    int p = j * 4096 + tid * 16;
    int r = p >> 7;
    int sl = (p >> 4) & 7;
    sr[j] = r;
    sch[j] = (sl ^ (r & 7)) * 8;
  }
  char* lbaseA = (char*)lA + wave * 1024;
  char* lbaseB = (char*)lB + wave * 1024;

  for (int k0 = 0; k0 < K; k0 += 64) {
#pragma unroll
    for (int j = 0; j < 4; j++) {
      gload_lds16(A + (brow + sr[j]) * K + k0 + sch[j], lbaseA + j * 4096);
      gload_lds16(Bt + (bcol + sr[j]) * K + k0 + sch[j], lbaseB + j * 4096);
    }
    __syncthreads();
#pragma unroll
    for (int ks = 0; ks < 2; ks++) {
      bf16x8 af[4], bfr[4];
#pragma unroll
      for (int m = 0; m < 4; m++) {
        int ra = wr * 64 + m * 16 + c;
        af[m] = *(const bf16x8*)((const char*)lA + ra * 128 + ((ks * 64 + g * 16) ^ ((ra & 7) << 4)));
        int rb = wc * 64 + m * 16 + c;
        bfr[m] = *(const bf16x8*)((const char*)lB + rb * 128 + ((ks * 64 + g * 16) ^ ((rb & 7) << 4)));
      }
      __builtin_amdgcn_s_setprio(1);
#pragma unroll
      for (int m = 0; m < 4; m++)
#pragma unroll
        for (int n = 0; n < 4; n++)
          acc[m][n] = __builtin_amdgcn_mfma_f32_16x16x32_bf16(af[m], bfr[n], acc[m][n], 0, 0, 0);
      __builtin_amdgcn_s_setprio(0);
    }
    __syncthreads();
  }

  const float scale = (mat == 0) ? 0.180336880111120f /*0.125*log2(e)*/ : 1.0f;
#pragma unroll
  for (int m = 0; m < 4; m++) {
#pragma unroll
    for (int n = 0; n < 4; n++) {
      long row0 = brow + wr * 64 + m * 16 + g * 4;
      long col = bcol + wc * 64 + n * 16 + c;
      float bv_ = bias[col];
      if (mat == 2) {  // V: transposed per-head write -> Vt[b][h][d][s]
        long b_ = row0 >> 11, s = row0 & 2047;
        size_t base = ((size_t)(b_ * NH + (col >> 6)) * 64 + (col & 63)) * SS + s;
        ushort4 pk;
        pk.x = f2bf(acc[m][n][0] + bv_);
        pk.y = f2bf(acc[m][n][1] + bv_);
        pk.z = f2bf(acc[m][n][2] + bv_);
        pk.w = f2bf(acc[m][n][3] + bv_);
        *(ushort4*)(Vtp + base) = pk;
      } else {
        unsigned short* C = mat ? Kb : Qb;
#pragma unroll
        for (int r = 0; r < 4; r++)
          C[(row0 + r) * N + col] = f2bf((acc[m][n][r] + bv_) * scale);
      }
    }
  }
}

// ---------------- O-projection GEMM (fp32 out) ----------------
__global__ __launch_bounds__(256) void k_gemmO(const unsigned short* __restrict__ A,
                                               const unsigned short* __restrict__ Bt,
                                               const float* __restrict__ bias,
                                               float* __restrict__ Cout) {
  constexpr int K = 1024, N = 1024;
  __shared__ unsigned short lA[128 * 64];
  __shared__ unsigned short lB[128 * 64];
  const int tid = threadIdx.x;
  const int lane = tid & 63, wave = tid >> 6;
  const int wr = wave >> 1, wc = wave & 1;
  const int g = lane >> 4, c = lane & 15;

  const int bid = blockIdx.x;
  const int xcd = bid & 7, idx = bid >> 3;
  const int by = xcd * 8 + (idx >> 3), bx = idx & 7;
  const long brow = (long)by * 128, bcol = (long)bx * 128;

  f32x4 acc[4][4] = {};

  int sr[4], sch[4];
#pragma unroll
  for (int j = 0; j < 4; j++) {
    int p = j * 4096 + tid * 16;
    int r = p >> 7;
    int sl = (p >> 4) & 7;
    sr[j] = r;
    sch[j] = (sl ^ (r & 7)) * 8;
  }
  char* lbaseA = (char*)lA + wave * 1024;
  char* lbaseB = (char*)lB + wave * 1024;

  for (int k0 = 0; k0 < K; k0 += 64) {
#pragma unroll
    for (int j = 0; j < 4; j++) {
      gload_lds16(A + (brow + sr[j]) * K + k0 + sch[j], lbaseA + j * 4096);
      gload_lds16(Bt + (bcol + sr[j]) * K + k0 + sch[j], lbaseB + j * 4096);
    }
    __syncthreads();
#pragma unroll
    for (int ks = 0; ks < 2; ks++) {
      bf16x8 af[4], bfr[4];
#pragma unroll
      for (int m = 0; m < 4; m++) {
        int ra = wr * 64 + m * 16 + c;
        af[m] = *(const bf16x8*)((const char*)lA + ra * 128 + ((ks * 64 + g * 16) ^ ((ra & 7) << 4)));
        int rb = wc * 64 + m * 16 + c;
        bfr[m] = *(const bf16x8*)((const char*)lB + rb * 128 + ((ks * 64 + g * 16) ^ ((rb & 7) << 4)));
      }
      __builtin_amdgcn_s_setprio(1);
#pragma unroll
      for (int m = 0; m < 4; m++)
#pragma unroll
        for (int n = 0; n < 4; n++)
          acc[m][n] = __builtin_amdgcn_mfma_f32_16x16x32_bf16(af[m], bfr[n], acc[m][n], 0, 0, 0);
      __builtin_amdgcn_s_setprio(0);
    }
    __syncthreads();
  }

#pragma unroll
  for (int m = 0; m < 4; m++) {
#pragma unroll
    for (int n = 0; n < 4; n++) {
      long row0 = brow + wr * 64 + m * 16 + g * 4;
      long col = bcol + wc * 64 + n * 16 + c;
      float bv = bias[col];
#pragma unroll
      for (int r = 0; r < 4; r++)
        Cout[(row0 + r) * N + col] = acc[m][n][r] + bv;
    }
  }
}

// ---------------- flash attention (exact R13-measured structure) --------------
// Swapped QK^T + in-register softmax (no per-tile cross-lane ops) +
// counted-vmcnt pipeline: K staged distance-2 (3 slots), V distance-1 (2 slots),
// steady-state wait = vmcnt(2), ONE raw s_barrier per tile, never drain-0
// in-loop. Guard-based softmax: mst init 8.0 (log2 domain), full rescale only
// if any score exceeds mst+8 (row-sum deferred to epilogue; factors row-uniform).
// Score tile S^T = mfma(K,Q): [key = ct*16+g*4+r][q = rt*16+c].
__global__ __launch_bounds__(256, 4) void k_flash(const unsigned short* __restrict__ Q,
                                                  const unsigned short* __restrict__ Kb,
                                                  const unsigned short* __restrict__ Vt,
                                                  const int* __restrict__ mask,
                                                  const int* __restrict__ flg,
                                                  unsigned short* __restrict__ O) {
  __shared__ unsigned short lK[3][4096];   // 3 K slots (24 KB), swizzled rows
  __shared__ unsigned short lV[2][4096];   // 2 V slots (16 KB), swizzled rows
  const int tid = threadIdx.x, lane = tid & 63, w = tid >> 6;
  const int g = lane >> 4, c = lane & 15;

  const int bid = blockIdx.x;
  const int xcd = bid & 7, jj = bid >> 3;
  const int qb = jj & 15, Ghi = jj >> 4;
  const int G = xcd * 8 + Ghi;
  const int h = G & 15, b = G >> 4;

  const int q0 = qb * 128 + w * 32;
  const long mrow0 = (long)b * SS + q0;

  const unsigned short* Kbase = Kb + (size_t)b * SS * 1024 + h * 64;
  const unsigned short* Vbase = Vt + (size_t)((b * NH + h) * 64) * SS;
  const int* Mbase = mask + ((size_t)b * SS + q0) * SS;
  const int* Fbase = flg + ((size_t)b * 16 + qb) * 32;

  // uniform "all tiles unmasked" flag (loads age older than all staging loads)
  int allok = 1;
#pragma unroll
  for (int i = 0; i < 32; i++) allok &= Fbase[i];
  allok = __builtin_amdgcn_readfirstlane(allok);

  // Q fragments (registers for whole kernel)
  bf16x8 qf[2][2];
#pragma unroll
  for (int rt = 0; rt < 2; rt++)
#pragma unroll
    for (int ks = 0; ks < 2; ks++)
      qf[rt][ks] = *(const bf16x8*)(Q + (mrow0 + rt * 16 + c) * 1024 + h * 64 + ks * 32 + g * 8);

  // staging: linear LDS dest; pre-swizzled global source (tile row r holds
  // 16B-slot t = source slot t^(r&7))
  const int pB = tid * 16;
  const int r0 = pB >> 7;
  const int co = (((pB >> 4) & 7) ^ (r0 & 7)) * 8;
  const unsigned short* gK = Kbase + (size_t)r0 * 1024 + co;
  const unsigned short* gV = Vbase + (size_t)r0 * SS + co;
  const int wb = w * 1024;

  char* sk0 = (char*)&lK[0][0];
  char* sk1 = (char*)&lK[1][0];
  char* sk2 = (char*)&lK[2][0];
  char* sv0 = (char*)&lV[0][0];
  char* sv1 = (char*)&lV[1][0];

#define STAGE_K(kt_, dst_) do { \
    const unsigned short* aK_ = gK + (size_t)(kt_) * (64 * 1024); \
    gload_lds16(aK_, (dst_) + wb); \
    gload_lds16(aK_ + 32 * 1024, (dst_) + wb + 4096); } while (0)
#define STAGE_V(kt_, dst_) do { \
    const unsigned short* aV_ = gV + (size_t)(kt_) * 64; \
    gload_lds16(aV_, (dst_) + wb); \
    gload_lds16(aV_ + 32 * (size_t)SS, (dst_) + wb + 4096); } while (0)

  // prologue issue order (ages): K0, V0, K1  -> vmcnt(2) at iter0 leaves K1
  STAGE_K(0, sk0);
  STAGE_V(0, sv0);
  STAGE_K(1, sk1);

  float mst[2] = {8.0f, 8.0f}, lst[2] = {0.0f, 0.0f};
  f32x4 o[2][4] = {};  // O^T frag: [d = ct*16+g*4+r][q = rt*16+c]

  for (int kt = 0; kt < SS / 64; kt++) {
    // wait for K(kt) and V(kt); leaves K(kt+1) in flight (2 loads)
    if (kt < SS / 64 - 1) asm volatile("s_waitcnt vmcnt(2)" ::: "memory");
    else                  asm volatile("s_waitcnt vmcnt(0)" ::: "memory");
    __builtin_amdgcn_s_barrier();
    __builtin_amdgcn_sched_barrier(0);
    // issue next tiles: V(kt+1) FIRST (must age older than K(kt+2))
    if (kt + 1 < SS / 64) STAGE_V(kt + 1, sv1);
    if (kt + 2 < SS / 64) STAGE_K(kt + 2, sk2);

    // K fragments (conflict-free via XOR swizzle)
    bf16x8 kf[4][2];
#pragma unroll
    for (int ct = 0; ct < 4; ct++)
#pragma unroll
      for (int ks = 0; ks < 2; ks++)
        kf[ct][ks] = *(const bf16x8*)(sk0 + (ct * 16 + c) * 128 +
                                      ((ks * 64 + g * 16) ^ ((c & 7) << 4)));

    // QK^T with C-in = -mst  (scores arrive pre-shifted: sc = S - mst)
    f32x4 sc[2][4];
#pragma unroll
    for (int rt = 0; rt < 2; rt++)
#pragma unroll
      for (int ct = 0; ct < 4; ct++)
#pragma unroll
        for (int r = 0; r < 4; r++) sc[rt][ct][r] = -mst[rt];
    __builtin_amdgcn_s_setprio(1);
#pragma unroll
    for (int ks = 0; ks < 2; ks++)
#pragma unroll
      for (int rt = 0; rt < 2; rt++)
#pragma unroll
        for (int ct = 0; ct < 4; ct++)
          sc[rt][ct] = __builtin_amdgcn_mfma_f32_16x16x32_bf16(kf[ct][ks], qf[rt][ks], sc[rt][ct], 0, 0, 0);
    __builtin_amdgcn_s_setprio(0);

    if (!allok) {  // general-mask slow path (never taken for all-ones mask)
      const int key0 = kt * 64;
#pragma unroll
      for (int rt = 0; rt < 2; rt++)
#pragma unroll
        for (int ct = 0; ct < 4; ct++)
#pragma unroll
          for (int r = 0; r < 4; r++) {
            int mv = Mbase[(size_t)(rt * 16 + c) * SS + key0 + ct * 16 + g * 4 + r];
            if (mv == 0) sc[rt][ct][r] = -1e10f;
          }
    }

    // per-lane guard max (trigger iff true max > mst + 8)
    float pm[2];
#pragma unroll
    for (int rt = 0; rt < 2; rt++) {
      f32x4 m4;
#pragma unroll
      for (int r = 0; r < 4; r++)
        m4[r] = fmaxf(fmaxf(sc[rt][0][r], sc[rt][1][r]), fmaxf(sc[rt][2][r], sc[rt][3][r]));
      pm[rt] = fmaxf(fmaxf(m4[0], m4[1]), fmaxf(m4[2], m4[3]));
    }
    if (__any((pm[0] > 8.0f) | (pm[1] > 8.0f))) {
      // rare full rescale: factors are row-uniform after the cross-lane max
#pragma unroll
      for (int rt = 0; rt < 2; rt++) {
        float tmv = pm[rt];
        tmv = fmaxf(tmv, __shfl_xor(tmv, 16, 64));
        tmv = fmaxf(tmv, __shfl_xor(tmv, 32, 64));
        float dpos = fmaxf(tmv, 0.0f);   // mnew - mold
        float sf = ex2(-dpos);
        mst[rt] += dpos;
        lst[rt] *= sf;
#pragma unroll
        for (int ct = 0; ct < 4; ct++)
#pragma unroll
          for (int r = 0; r < 4; r++) { o[rt][ct][r] *= sf; sc[rt][ct][r] -= dpos; }
      }
    }

    // P = 2^sc; per-lane partial row-sum (reduced once in epilogue);
    // pack + permlane-redistribute into PV B-fragments (no LDS)
    union PU { unsigned int wd[4]; bf16x8 v; };
    PU pf[2][2];
#pragma unroll
    for (int rt = 0; rt < 2; rt++) {
      f32x4 ts4 = {0.0f, 0.0f, 0.0f, 0.0f};
      unsigned int Wd[4][2];
#pragma unroll
      for (int ct = 0; ct < 4; ct++) {
        f32x4 p;
#pragma unroll
        for (int r = 0; r < 4; r++) {
          p[r] = ex2(sc[rt][ct][r]);
          ts4[r] += p[r];
        }
        Wd[ct][0] = cvtpk(p[0], p[1]);
        Wd[ct][1] = cvtpk(p[2], p[3]);
      }
#pragma unroll
      for (int ks = 0; ks < 2; ks++)
#pragma unroll
        for (int hh = 0; hh < 2; hh++) {
          unsigned int a = Wd[2 * ks][hh], bb = Wd[2 * ks + 1][hh];
          swap32(a, bb);  // a={A_lo,B_lo}, bb={A_hi,B_hi}
          swap16(a, bb);  // interleave 4-row groups
          pf[rt][ks].wd[hh] = a;
          pf[rt][ks].wd[2 + hh] = bb;
        }
      lst[rt] += (ts4[0] + ts4[1]) + (ts4[2] + ts4[3]);
    }

    // V fragments + PV
    bf16x8 vf[4][2];
#pragma unroll
    for (int ct = 0; ct < 4; ct++)
#pragma unroll
      for (int ks = 0; ks < 2; ks++)
        vf[ct][ks] = *(const bf16x8*)(sv0 + (ct * 16 + c) * 128 +
                                      ((ks * 64 + g * 16) ^ ((c & 7) << 4)));
    __builtin_amdgcn_s_setprio(1);
#pragma unroll
    for (int rt = 0; rt < 2; rt++)
#pragma unroll
      for (int ct = 0; ct < 4; ct++)
#pragma unroll
        for (int ks = 0; ks < 2; ks++)
          o[rt][ct] = __builtin_amdgcn_mfma_f32_16x16x32_bf16(vf[ct][ks], pf[rt][ks].v, o[rt][ct], 0, 0, 0);
    __builtin_amdgcn_s_setprio(0);

    // rotate slots
    char* tk = sk0; sk0 = sk1; sk1 = sk2; sk2 = tk;
    char* tv = sv0; sv0 = sv1; sv1 = tv;
  }

  // epilogue: one cross-lane reduce of the deferred row-sums, then write O
#pragma unroll
  for (int rt = 0; rt < 2; rt++) {
    float t = lst[rt];
    t += __shfl_xor(t, 16, 64);
    t += __shfl_xor(t, 32, 64);
    float inv = 1.0f / t;
#pragma unroll
    for (int ct = 0; ct < 4; ct++) {
      uint2 pk;
      pk.x = cvtpk(o[rt][ct][0] * inv, o[rt][ct][1] * inv);
      pk.y = cvtpk(o[rt][ct][2] * inv, o[rt][ct][3] * inv);
      *(uint2*)(O + (mrow0 + rt * 16 + c) * 1024 + h * 64 + ct * 16 + g * 4) = pk;
    }
  }
#undef STAGE_K
#undef STAGE_V
}

extern "C" void kernel_launch(void* const* d_in, const int* in_sizes, int n_in,
                              void* d_out, int out_size, void* d_ws, size_t ws_size,
                              hipStream_t stream) {
  const float* x  = (const float*)d_in[0];
  const int* mask = (const int*)d_in[1];
  const float* Wq = (const float*)d_in[2];
  const float* bq = (const float*)d_in[3];
  const float* Wk = (const float*)d_in[4];
  const float* bk = (const float*)d_in[5];
  const float* Wv = (const float*)d_in[6];
  const float* bv = (const float*)d_in[7];
  const float* Wo = (const float*)d_in[8];
  const float* bo = (const float*)d_in[9];

  char* ws = (char*)d_ws;
  unsigned short* xb = (unsigned short*)ws;                        // 16 MiB (reused as O)
  unsigned short* Wt = (unsigned short*)(ws + (16ull << 20));      // 8 MiB (4 matrices)
  unsigned short* Qb = (unsigned short*)(ws + (24ull << 20));      // 16 MiB
  unsigned short* Kb = (unsigned short*)(ws + (40ull << 20));      // 16 MiB
  unsigned short* Vt = (unsigned short*)(ws + (56ull << 20));      // 16 MiB -> 72 MiB total
  int* flg = (int*)d_out;  // 8 KiB scratch; fully overwritten by final GEMM

  // fused preprocessing (conv_x | transW | maskflags)
  k_prep<<<11264, 256, 0, stream>>>(x, Wq, Wk, Wv, Wo, mask, xb, Wt, flg);
  // fused Q/K/V projections; Q scaled by 0.125*log2(e) (log2-domain softmax)
  k_gemmQKV<<<1536, 256, 0, stream>>>(xb, Wt, bq, bk, bv, Qb, Kb, Vt);
  k_flash<<<1024, 256, 0, stream>>>(Qb, Kb, Vt, mask, flg, xb);
  k_gemmO<<<512, 256, 0, stream>>>(xb, Wt + (3u << 20), bo, (float*)d_out);
}